// Round 3
// baseline (94.242 us; speedup 1.0000x reference)
//
#include <hip/hip_runtime.h>
#include <hip/hip_bf16.h>

typedef unsigned short u16;
typedef __attribute__((ext_vector_type(8))) __bf16 bf16x8;
typedef __attribute__((ext_vector_type(4))) float f32x4;
typedef __attribute__((ext_vector_type(4))) unsigned short u16x4;

#define DEV static __device__ __forceinline__

static constexpr int N = 2048, D = 1024;
static constexpr int NQ = 256;     // active query rows (q//16 == kv%16 => q < 256)
static constexpr float EPS = 1e-5f;

DEV u16 f2b(float f) {
  union { float f; unsigned u; } x; x.f = f;
  unsigned r = x.u + 0x7FFFu + ((x.u >> 16) & 1u);   // RNE
  return (u16)(r >> 16);
}
DEV float b2f(u16 h) {
  union { unsigned u; float f; } x; x.u = ((unsigned)h) << 16;
  return x.f;
}

DEV void async16(const void* g, void* l) {
  __builtin_amdgcn_global_load_lds(
      (const __attribute__((address_space(1))) unsigned int*)g,
      (__attribute__((address_space(3))) unsigned int*)l, 16, 0, 0);
}

// ---------------- LayerNorm over D=1024 -> bf16 ----------------
__global__ __launch_bounds__(256) void k_ln_x(const float* __restrict__ x, u16* __restrict__ xn) {
  const int row = blockIdx.x;
  const int t = threadIdx.x;
  const float4 v = ((const float4*)(x + (size_t)row * D))[t];
  float s  = v.x + v.y + v.z + v.w;
  float ss = v.x * v.x + v.y * v.y + v.z * v.z + v.w * v.w;
  __shared__ float red0[4], red1[4];
  for (int off = 32; off; off >>= 1) { s += __shfl_xor(s, off, 64); ss += __shfl_xor(ss, off, 64); }
  const int w = t >> 6, l = t & 63;
  if (l == 0) { red0[w] = s; red1[w] = ss; }
  __syncthreads();
  s  = red0[0] + red0[1] + red0[2] + red0[3];
  ss = red1[0] + red1[1] + red1[2] + red1[3];
  const float mu = s * (1.0f / D);
  const float var = ss * (1.0f / D) - mu * mu;
  const float rs = rsqrtf(var + EPS);
  u16x4 o;
  o.x = f2b((v.x - mu) * rs); o.y = f2b((v.y - mu) * rs);
  o.z = f2b((v.z - mu) * rs); o.w = f2b((v.w - mu) * rs);
  ((u16x4*)(xn + (size_t)row * D))[t] = o;
}

// ---------------- transpose weights f32 [K][N] -> bf16 [N][K] ----------------
__global__ __launch_bounds__(256) void k_transpose_w(const float* __restrict__ wq, const float* __restrict__ wk,
                                                     const float* __restrict__ wv, const float* __restrict__ wo,
                                                     u16* __restrict__ wt) {
  const float* src = blockIdx.z == 0 ? wq : blockIdx.z == 1 ? wk : blockIdx.z == 2 ? wv : wo;
  u16* dst = wt + (size_t)blockIdx.z * D * D;
  __shared__ float tile[32][33];
  const int k0 = blockIdx.y * 32, n0 = blockIdx.x * 32;
  const int t = threadIdx.x;
  const int c = t & 31, r4 = t >> 5;
#pragma unroll
  for (int p = 0; p < 4; ++p) { int r = r4 + p * 8; tile[r][c] = src[(size_t)(k0 + r) * D + n0 + c]; }
  __syncthreads();
#pragma unroll
  for (int p = 0; p < 4; ++p) { int r = r4 + p * 8; dst[(size_t)(n0 + r) * D + k0 + c] = f2b(tile[c][r]); }
}

// ---------------- 128x128 bf16 MFMA GEMM tile (A [M][K], BT [N][K], C f32) ----------------
template<bool ADD>
DEV void gemm128(const u16* __restrict__ A, const u16* __restrict__ BT,
                 float* __restrict__ C, const float* __restrict__ ADDSRC,
                 int row0, int col0, int ldc) {
  constexpr int K = 1024, BK = 32;
  __shared__ __align__(16) u16 As[128 * BK];
  __shared__ __align__(16) u16 Bs[128 * BK];
  const int t = threadIdx.x;
  const int w = t >> 6, l = t & 63;
  const int wm = (w & 1) << 6, wn = (w >> 1) << 6;

  f32x4 acc[4][4];
#pragma unroll
  for (int i = 0; i < 4; ++i)
#pragma unroll
    for (int j = 0; j < 4; ++j) acc[i][j] = (f32x4){0.f, 0.f, 0.f, 0.f};

  const int sr = t >> 2;        // staged row 0..63 (chunk = t -> lds byte t*16: wave-linear)
  const int sc = (t & 3) << 3;  // k offset 0,8,16,24
  const u16* gA0 = A + (size_t)(row0 + sr) * K + sc;
  const u16* gA1 = gA0 + (size_t)64 * K;
  const u16* gB0 = BT + (size_t)(col0 + sr) * K + sc;
  const u16* gB1 = gB0 + (size_t)64 * K;
  u16* lA0 = &As[sr * BK + sc];
  u16* lA1 = &As[(sr + 64) * BK + sc];
  u16* lB0 = &Bs[sr * BK + sc];
  u16* lB1 = &Bs[(sr + 64) * BK + sc];

  const int fr = l & 15;          // A-row / B-col within 16x16 frag
  const int kc = (l >> 4) << 3;   // k chunk (8 contiguous)

  for (int k0 = 0; k0 < K; k0 += BK) {
    async16(gA0 + k0, lA0);
    async16(gA1 + k0, lA1);
    async16(gB0 + k0, lB0);
    async16(gB1 + k0, lB1);
    __syncthreads();   // drains vmcnt -> staged data visible
    bf16x8 af[4], bfr[4];
#pragma unroll
    for (int i = 0; i < 4; ++i) af[i] = *(const bf16x8*)&As[(wm + i * 16 + fr) * BK + kc];
#pragma unroll
    for (int j = 0; j < 4; ++j) bfr[j] = *(const bf16x8*)&Bs[(wn + j * 16 + fr) * BK + kc];
#pragma unroll
    for (int i = 0; i < 4; ++i)
#pragma unroll
      for (int j = 0; j < 4; ++j)
        acc[i][j] = __builtin_amdgcn_mfma_f32_16x16x32_bf16(af[i], bfr[j], acc[i][j], 0, 0, 0);
    __syncthreads();   // all reads done before next stage overwrites
  }

  const int rq = (l >> 4) << 2;
#pragma unroll
  for (int i = 0; i < 4; ++i)
#pragma unroll
    for (int j = 0; j < 4; ++j) {
      const int col = col0 + wn + j * 16 + fr;
#pragma unroll
      for (int r = 0; r < 4; ++r) {
        const int row = row0 + wm + i * 16 + rq + r;
        float v = acc[i][j][r];
        if constexpr (ADD) v += ADDSRC[(size_t)row * ldc + col];
        C[(size_t)row * ldc + col] = v;
      }
    }
}

// fused QKV: blocks 0..255 -> kv GEMM (M=2048, N=2048 over [w_k|w_v]); 256..271 -> q GEMM (M=256, N=1024)
__global__ __launch_bounds__(256) void k_gemm_qkv(const u16* __restrict__ xn, const u16* __restrict__ wt,
                                                  float* __restrict__ kvb, float* __restrict__ qb) {
  const int bid = blockIdx.x;
  const u16* BT; float* C; int r0, c0, ldc;
  if (bid < 256) { BT = wt + (size_t)D * D; C = kvb; r0 = (bid >> 4) * 128; c0 = (bid & 15) * 128; ldc = 2 * D; }
  else { const int q = bid - 256; BT = wt; C = qb; r0 = (q >> 3) * 128; c0 = (q & 7) * 128; ldc = D; }
  gemm128<false>(xn, BT, C, nullptr, r0, c0, ldc);
}

__global__ __launch_bounds__(256) void k_gemm_o(const u16* __restrict__ attnb, const u16* __restrict__ wt,
                                                const float* __restrict__ x, float* __restrict__ out) {
  const int bm = blockIdx.x >> 3, bn = blockIdx.x & 7;
  gemm128<true>(attnb, wt + (size_t)3 * D * D, out, x, bm * 128, bn * 128, D);
}

// ---------------- per-head LN (dh=64) on q (256 rows) and k (2048 rows) -> bf16 ----------------
__global__ __launch_bounds__(256) void k_head_ln(const float* __restrict__ qb, const float* __restrict__ kvb,
                                                 u16* __restrict__ qh, u16* __restrict__ kh) {
  const int gid = blockIdx.x * 4 + (threadIdx.x >> 6);
  const int l = threadIdx.x & 63;
  const float* src; u16* dst; int row, head, ld;
  if (gid < NQ * 16) { row = gid >> 4; head = gid & 15; src = qb;  ld = D;     dst = qh; }
  else { const int g = gid - NQ * 16; row = g >> 4; head = g & 15; src = kvb; ld = 2 * D; dst = kh; }
  const float v = src[(size_t)row * ld + head * 64 + l];
  float s = v, ss = v * v;
  for (int off = 32; off; off >>= 1) { s += __shfl_xor(s, off, 64); ss += __shfl_xor(ss, off, 64); }
  const float mu = s * (1.0f / 64);
  const float var = ss * (1.0f / 64) - mu * mu;
  const float rs = rsqrtf(var + EPS);
  dst[(size_t)row * D + head * 64 + l] = f2b((v - mu) * rs);
}

// ---------------- block-sparse attention: block = (head h, q-block b), kv rows {b+16j} ----------------
__global__ __launch_bounds__(256) void k_attn(const u16* __restrict__ qh, const u16* __restrict__ kh,
                                              const float* __restrict__ kvb, u16* __restrict__ attnb) {
  const int h = blockIdx.x >> 4, b = blockIdx.x & 15;
  __shared__ float q_s[16][64];
  __shared__ u16  k_u[128][68];                 // padded: breaks stride-128B bank conflict
  __shared__ __align__(8) u16 v_u[128][64];
  __shared__ float s_s[16][132];
  __shared__ float inv_den[16];
  const int t = threadIdx.x;

  for (int idx = t; idx < 16 * 64; idx += 256) {
    const int i = idx >> 6, d = idx & 63;
    q_s[i][d] = b2f(qh[(size_t)(b * 16 + i) * D + h * 64 + d]);
  }
  for (int idx = t; idx < 128 * 64; idx += 256) {
    const int j = idx >> 6, d = idx & 63;
    const int kr = b + 16 * j;
    k_u[j][d] = kh[(size_t)kr * D + h * 64 + d];
    v_u[j][d] = f2b(kvb[(size_t)kr * 2 * D + D + h * 64 + d]);
  }
  __syncthreads();

  const int i = t >> 4;      // q row within block
  const int sub = t & 15;
#pragma unroll
  for (int jj = 0; jj < 8; ++jj) {
    const int j = sub + 16 * jj;
    float acc = 0.f;
#pragma unroll
    for (int d = 0; d < 64; ++d) acc += q_s[i][d] * b2f(k_u[j][d]);
    s_s[i][j] = acc * 0.125f;   // sm_scale = 1/sqrt(64)
  }
  __syncthreads();
  float m = -1e30f;
#pragma unroll
  for (int jj = 0; jj < 8; ++jj) m = fmaxf(m, s_s[i][sub + 16 * jj]);
  for (int off = 1; off < 16; off <<= 1) m = fmaxf(m, __shfl_xor(m, off, 64));
  float sum = 0.f;
#pragma unroll
  for (int jj = 0; jj < 8; ++jj) {
    const int j = sub + 16 * jj;
    const float p = __expf(s_s[i][j] - m);
    s_s[i][j] = p;
    sum += p;
  }
  for (int off = 1; off < 16; off <<= 1) sum += __shfl_xor(sum, off, 64);
  if (sub == 0) inv_den[i] = 1.0f / sum;
  __syncthreads();

  const int db = sub << 2;
  float a0 = 0, a1 = 0, a2 = 0, a3 = 0;
  for (int j = 0; j < 128; ++j) {
    const float p = s_s[i][j];
    a0 += p * b2f(v_u[j][db + 0]);
    a1 += p * b2f(v_u[j][db + 1]);
    a2 += p * b2f(v_u[j][db + 2]);
    a3 += p * b2f(v_u[j][db + 3]);
  }
  const float inv = inv_den[i];
  u16x4 o;
  o.x = f2b(a0 * inv); o.y = f2b(a1 * inv); o.z = f2b(a2 * inv); o.w = f2b(a3 * inv);
  *(u16x4*)&attnb[(size_t)(b * 16 + i) * D + h * 64 + db] = o;
}

// ---------------- residual passthrough: out = x (rows < 256 later overwritten by gemm_o) ----------------
__global__ __launch_bounds__(256) void k_copy(const float* __restrict__ x, float* __restrict__ out) {
  const int i = blockIdx.x * 256 + threadIdx.x;
  ((float4*)out)[i] = ((const float4*)x)[i];
}

extern "C" void kernel_launch(void* const* d_in, const int* in_sizes, int n_in,
                              void* d_out, int out_size, void* d_ws, size_t ws_size,
                              hipStream_t stream) {
  const float* x  = (const float*)d_in[0];
  const float* wq = (const float*)d_in[1];
  const float* wk = (const float*)d_in[2];
  const float* wv = (const float*)d_in[3];
  const float* wo = (const float*)d_in[4];
  float* out = (float*)d_out;
  char* ws = (char*)d_ws;

  // ws layout (34 MiB total)
  u16*   xn    = (u16*)(ws + 0);           // [2048][1024] bf16
  u16*   wt    = (u16*)(ws + 4194304);     // [4][1024][1024] bf16 transposed (q,k,v,o)
  float* kvb   = (float*)(ws + 12582912);  // [2048][2048] f32 (k | v)
  float* qb    = (float*)(ws + 29360128);  // [256][1024] f32
  u16*   qh    = (u16*)(ws + 30408704);    // [256][1024] bf16 (per-head LN'd q)
  u16*   kh    = (u16*)(ws + 30932992);    // [2048][1024] bf16 (per-head LN'd k)
  u16*   attnb = (u16*)(ws + 35127296);    // [256][1024] bf16

  k_ln_x<<<dim3(N), dim3(256), 0, stream>>>(x, xn);
  k_transpose_w<<<dim3(32, 32, 4), dim3(256), 0, stream>>>(wq, wk, wv, wo, wt);
  k_gemm_qkv<<<dim3(272), dim3(256), 0, stream>>>(xn, wt, kvb, qb);
  k_head_ln<<<dim3((NQ * 16 + N * 16) / 4), dim3(256), 0, stream>>>(qb, kvb, qh, kh);
  k_attn<<<dim3(256), dim3(256), 0, stream>>>(qh, kh, kvb, attnb);
  k_copy<<<dim3(N * D / 4 / 256), dim3(256), 0, stream>>>(x, out);
  k_gemm_o<<<dim3(16), dim3(256), 0, stream>>>(attnb, wt, x, out);
}

// Round 4
// 65.495 us; speedup vs baseline: 1.4389x; 1.4389x over previous
//
#include <hip/hip_runtime.h>
#include <hip/hip_bf16.h>

typedef unsigned short u16;
typedef __attribute__((ext_vector_type(8))) __bf16 bf16x8;
typedef __attribute__((ext_vector_type(4))) float f32x4;
typedef __attribute__((ext_vector_type(4))) unsigned short u16x4;

#define DEV static __device__ __forceinline__

static constexpr int N = 2048, D = 1024;
static constexpr float EPS = 1e-5f;

DEV u16 f2b(float f) {
  union { float f; unsigned u; } x; x.f = f;
  unsigned r = x.u + 0x7FFFu + ((x.u >> 16) & 1u);   // RNE
  return (u16)(r >> 16);
}
DEV float b2f(u16 h) {
  union { unsigned u; float f; } x; x.u = ((unsigned)h) << 16;
  return x.f;
}

DEV void async16(const void* g, void* l) {
  __builtin_amdgcn_global_load_lds(
      (const __attribute__((address_space(1))) unsigned int*)g,
      (__attribute__((address_space(3))) unsigned int*)l, 16, 0, 0);
}

// ---- fused pre: blocks [0,2048) = LayerNorm(x) rows -> bf16; [2048,6144) = transpose w -> bf16 [N][K]
__global__ __launch_bounds__(256) void k_pre(const float* __restrict__ x,
                                             const float* __restrict__ wq, const float* __restrict__ wk,
                                             const float* __restrict__ wv, const float* __restrict__ wo,
                                             u16* __restrict__ xn, u16* __restrict__ wt) {
  const int t = threadIdx.x;
  if (blockIdx.x < 2048) {
    const int row = blockIdx.x;
    const float4 v = ((const float4*)(x + (size_t)row * D))[t];
    float s  = v.x + v.y + v.z + v.w;
    float ss = v.x * v.x + v.y * v.y + v.z * v.z + v.w * v.w;
    __shared__ float red0[4], red1[4];
    for (int off = 32; off; off >>= 1) { s += __shfl_xor(s, off, 64); ss += __shfl_xor(ss, off, 64); }
    const int w = t >> 6, l = t & 63;
    if (l == 0) { red0[w] = s; red1[w] = ss; }
    __syncthreads();
    s  = red0[0] + red0[1] + red0[2] + red0[3];
    ss = red1[0] + red1[1] + red1[2] + red1[3];
    const float mu = s * (1.0f / D);
    const float var = ss * (1.0f / D) - mu * mu;
    const float rs = rsqrtf(var + EPS);
    u16x4 o;
    o.x = f2b((v.x - mu) * rs); o.y = f2b((v.y - mu) * rs);
    o.z = f2b((v.z - mu) * rs); o.w = f2b((v.w - mu) * rs);
    ((u16x4*)(xn + (size_t)row * D))[t] = o;
  } else {
    const int bid = blockIdx.x - 2048;
    const int z = bid >> 10, rem = bid & 1023;
    const float* src = z == 0 ? wq : z == 1 ? wk : z == 2 ? wv : wo;
    u16* dst = wt + (size_t)z * D * D;
    __shared__ float tile[32][33];
    const int k0 = (rem >> 5) * 32, n0 = (rem & 31) * 32;
    const int c = t & 31, r4 = t >> 5;
#pragma unroll
    for (int p = 0; p < 4; ++p) { int r = r4 + p * 8; tile[r][c] = src[(size_t)(k0 + r) * D + n0 + c]; }
    __syncthreads();
#pragma unroll
    for (int p = 0; p < 4; ++p) { int r = r4 + p * 8; dst[(size_t)(n0 + r) * D + k0 + c] = f2b(tile[c][r]); }
  }
}

// ---- 128xBN bf16 MFMA GEMM tile (A [M][1024], BT [N][1024]), K-range [kbeg,kend) ----
template<int BN>
DEV void gemm_tile(const u16* __restrict__ A, const u16* __restrict__ BT,
                   float* __restrict__ C, int row0, int col0, int ldc, int kbeg, int kend) {
  constexpr int K = 1024, BK = 32, NJ = BN / 32;
  __shared__ __align__(16) u16 As[128 * BK];
  __shared__ __align__(16) u16 Bs[BN * BK];
  const int t = threadIdx.x;
  const int w = t >> 6, l = t & 63;
  const int wm = (w & 1) << 6, wn = (w >> 1) * (BN / 2);

  f32x4 acc[4][NJ];
#pragma unroll
  for (int i = 0; i < 4; ++i)
#pragma unroll
    for (int j = 0; j < NJ; ++j) acc[i][j] = (f32x4){0.f, 0.f, 0.f, 0.f};

  const int sr = t >> 2;        // staged row (wave-linear LDS dest for global_load_lds)
  const int sc = (t & 3) << 3;  // k offset 0,8,16,24
  const u16* gA0 = A + (size_t)(row0 + sr) * K + sc;
  const u16* gA1 = gA0 + (size_t)64 * K;
  const u16* gB0 = BT + (size_t)(col0 + sr) * K + sc;
  const u16* gB1 = gB0 + (size_t)64 * K;
  u16* lA0 = &As[sr * BK + sc];
  u16* lA1 = &As[(sr + 64) * BK + sc];
  u16* lB0 = &Bs[sr * BK + sc];
  u16* lB1 = &Bs[(sr + 64) * BK + sc];

  const int fr = l & 15;          // A-row / B-col within 16x16 frag
  const int kc = (l >> 4) << 3;   // k chunk (8 contiguous)

  for (int k0 = kbeg; k0 < kend; k0 += BK) {
    async16(gA0 + k0, lA0);
    async16(gA1 + k0, lA1);
    async16(gB0 + k0, lB0);
    if constexpr (BN == 128) async16(gB1 + k0, lB1);
    __syncthreads();   // drains vmcnt -> staged data visible
    bf16x8 af[4], bfr[NJ];
#pragma unroll
    for (int i = 0; i < 4; ++i) af[i] = *(const bf16x8*)&As[(wm + i * 16 + fr) * BK + kc];
#pragma unroll
    for (int j = 0; j < NJ; ++j) bfr[j] = *(const bf16x8*)&Bs[(wn + j * 16 + fr) * BK + kc];
#pragma unroll
    for (int i = 0; i < 4; ++i)
#pragma unroll
      for (int j = 0; j < NJ; ++j)
        acc[i][j] = __builtin_amdgcn_mfma_f32_16x16x32_bf16(af[i], bfr[j], acc[i][j], 0, 0, 0);
    __syncthreads();   // all reads done before next stage overwrites
  }

  const int rq = (l >> 4) << 2;
#pragma unroll
  for (int i = 0; i < 4; ++i)
#pragma unroll
    for (int j = 0; j < NJ; ++j) {
      const int col = col0 + wn + j * 16 + fr;
#pragma unroll
      for (int r = 0; r < 4; ++r) {
        const int row = row0 + wm + i * 16 + rq + r;
        C[(size_t)row * ldc + col] = acc[i][j][r];
      }
    }
}

// fused QKV: blocks [0,512) -> kv GEMM 128x64 tiles (M=2048, N=2048 over [w_k|w_v]); [512,544) -> q GEMM (M=256, N=1024)
__global__ __launch_bounds__(256) void k_gemm_qkv(const u16* __restrict__ xn, const u16* __restrict__ wt,
                                                  float* __restrict__ kvb, float* __restrict__ qb) {
  const int bid = blockIdx.x;
  const u16* BT; float* C; int r0, c0, ldc;
  if (bid < 512) { BT = wt + (size_t)D * D; C = kvb; r0 = (bid >> 5) * 128; c0 = (bid & 31) * 64; ldc = 2 * D; }
  else { const int q = bid - 512; BT = wt; C = qb; r0 = (q >> 4) * 128; c0 = (q & 15) * 64; ldc = D; }
  gemm_tile<64>(xn, BT, C, r0, c0, ldc, 0, 1024);
}

// output GEMM split-K: 16 output tiles (2x8 of 128x128) x 8 K-slices of 128 -> f32 partials
__global__ __launch_bounds__(256) void k_gemm_o(const u16* __restrict__ attnb, const u16* __restrict__ wt,
                                                float* __restrict__ part) {
  const int bid = blockIdx.x;
  const int tile = bid & 15, s = bid >> 4;
  const int bm = tile >> 3, bn = tile & 7;
  gemm_tile<128>(attnb, wt + (size_t)3 * D * D, part + (size_t)s * 256 * D,
                 bm * 128, bn * 128, D, s * 128, s * 128 + 128);
}

// ---- block-sparse attention with fused per-head LN of q and k ----
// block = (head h, q-block b); q rows b*16..b*16+15; kv rows {b+16j, j=0..127}
__global__ __launch_bounds__(256) void k_attn(const float* __restrict__ qb, const float* __restrict__ kvb,
                                              u16* __restrict__ attnb) {
  const int h = blockIdx.x >> 4, b = blockIdx.x & 15;
  __shared__ float q_s[16][68];
  __shared__ u16  k_u[128][68];                 // padded: breaks stride-128B bank conflict
  __shared__ u16  v_u[128][64];
  __shared__ float s_s[16][132];
  __shared__ float inv_den[16];
  const int t = threadIdx.x;

  // q: row i, 16 lanes per row, 4 elems each; LN over dh=64 via width-16 shuffle reduce
  {
    const int i = t >> 4, sub = t & 15;
    const float4 qv = *(const float4*)&qb[(size_t)(b * 16 + i) * D + h * 64 + sub * 4];
    float s  = qv.x + qv.y + qv.z + qv.w;
    float ss = qv.x * qv.x + qv.y * qv.y + qv.z * qv.z + qv.w * qv.w;
    for (int off = 1; off < 16; off <<= 1) { s += __shfl_xor(s, off, 16); ss += __shfl_xor(ss, off, 16); }
    const float mu = s * (1.0f / 64);
    const float var = ss * (1.0f / 64) - mu * mu;
    const float rs = rsqrtf(var + EPS);
    q_s[i][sub * 4 + 0] = (qv.x - mu) * rs;
    q_s[i][sub * 4 + 1] = (qv.y - mu) * rs;
    q_s[i][sub * 4 + 2] = (qv.z - mu) * rs;
    q_s[i][sub * 4 + 3] = (qv.w - mu) * rs;
  }
  // k: row j = t>>1, half = t&1 (32 elems); LN via xor-1 combine; write bf16
  {
    const int j = t >> 1, half = t & 1;
    const int kr = b + 16 * j;
    const float4* krow = (const float4*)&kvb[(size_t)kr * (2 * D) + h * 64 + half * 32];
    float4 kv4[8];
    float s = 0.f, ss = 0.f;
#pragma unroll
    for (int c = 0; c < 8; ++c) {
      const float4 vv = krow[c]; kv4[c] = vv;
      s += vv.x + vv.y + vv.z + vv.w;
      ss += vv.x * vv.x + vv.y * vv.y + vv.z * vv.z + vv.w * vv.w;
    }
    s += __shfl_xor(s, 1, 64); ss += __shfl_xor(ss, 1, 64);
    const float mu = s * (1.0f / 64);
    const float var = ss * (1.0f / 64) - mu * mu;
    const float rs = rsqrtf(var + EPS);
#pragma unroll
    for (int c = 0; c < 8; ++c) {
      u16x4 o;
      o.x = f2b((kv4[c].x - mu) * rs); o.y = f2b((kv4[c].y - mu) * rs);
      o.z = f2b((kv4[c].z - mu) * rs); o.w = f2b((kv4[c].w - mu) * rs);
      *(u16x4*)&k_u[j][half * 32 + c * 4] = o;
    }
  }
  // v: straight f32 -> bf16 copy into LDS (no LN)
  {
#pragma unroll
    for (int it = 0; it < 8; ++it) {
      const int idx = t + it * 256;            // 2048 float4 slots = 128 rows x 16
      const int j = idx >> 4, c = idx & 15;
      const int kr = b + 16 * j;
      const float4 vv = *(const float4*)&kvb[(size_t)kr * (2 * D) + D + h * 64 + c * 4];
      u16x4 o; o.x = f2b(vv.x); o.y = f2b(vv.y); o.z = f2b(vv.z); o.w = f2b(vv.w);
      *(u16x4*)&v_u[j][c * 4] = o;
    }
  }
  __syncthreads();

  const int i = t >> 4;      // q row within block
  const int sub = t & 15;
#pragma unroll
  for (int jj = 0; jj < 8; ++jj) {
    const int j = sub + 16 * jj;
    float acc = 0.f;
#pragma unroll
    for (int d = 0; d < 64; ++d) acc += q_s[i][d] * b2f(k_u[j][d]);
    s_s[i][j] = acc * 0.125f;   // sm_scale = 1/sqrt(64)
  }
  __syncthreads();
  float m = -1e30f;
#pragma unroll
  for (int jj = 0; jj < 8; ++jj) m = fmaxf(m, s_s[i][sub + 16 * jj]);
  for (int off = 1; off < 16; off <<= 1) m = fmaxf(m, __shfl_xor(m, off, 64));
  float sum = 0.f;
#pragma unroll
  for (int jj = 0; jj < 8; ++jj) {
    const int j = sub + 16 * jj;
    const float p = __expf(s_s[i][j] - m);
    s_s[i][j] = p;
    sum += p;
  }
  for (int off = 1; off < 16; off <<= 1) sum += __shfl_xor(sum, off, 64);
  if (sub == 0) inv_den[i] = 1.0f / sum;
  __syncthreads();

  const int db = sub << 2;
  float a0 = 0, a1 = 0, a2 = 0, a3 = 0;
  for (int j = 0; j < 128; ++j) {
    const float p = s_s[i][j];
    a0 += p * b2f(v_u[j][db + 0]);
    a1 += p * b2f(v_u[j][db + 1]);
    a2 += p * b2f(v_u[j][db + 2]);
    a3 += p * b2f(v_u[j][db + 3]);
  }
  const float inv = inv_den[i];
  u16x4 o;
  o.x = f2b(a0 * inv); o.y = f2b(a1 * inv); o.z = f2b(a2 * inv); o.w = f2b(a3 * inv);
  *(u16x4*)&attnb[(size_t)(b * 16 + i) * D + h * 64 + db] = o;
}

// ---- epilogue: out = x everywhere; rows < 256 additionally += sum of 8 K-partials ----
__global__ __launch_bounds__(256) void k_finish(const float* __restrict__ x, const float* __restrict__ part,
                                                float* __restrict__ out) {
  const int row = blockIdx.x, t = threadIdx.x;
  float4 v = ((const float4*)(x + (size_t)row * D))[t];
  if (row < 256) {
#pragma unroll
    for (int s = 0; s < 8; ++s) {
      const float4 p = ((const float4*)(part + ((size_t)s * 256 + row) * D))[t];
      v.x += p.x; v.y += p.y; v.z += p.z; v.w += p.w;
    }
  }
  ((float4*)(out + (size_t)row * D))[t] = v;
}

extern "C" void kernel_launch(void* const* d_in, const int* in_sizes, int n_in,
                              void* d_out, int out_size, void* d_ws, size_t ws_size,
                              hipStream_t stream) {
  const float* x  = (const float*)d_in[0];
  const float* wq = (const float*)d_in[1];
  const float* wk = (const float*)d_in[2];
  const float* wv = (const float*)d_in[3];
  const float* wo = (const float*)d_in[4];
  float* out = (float*)d_out;
  char* ws = (char*)d_ws;

  // ws layout (~39.3 MiB)
  u16*   xn    = (u16*)(ws + 0);           // [2048][1024] bf16
  u16*   wt    = (u16*)(ws + 4194304);     // [4][1024][1024] bf16 transposed (q,k,v,o)
  float* kvb   = (float*)(ws + 12582912);  // [2048][2048] f32 (k | v)
  float* qb    = (float*)(ws + 29360128);  // [256][1024] f32
  float* part  = (float*)(ws + 30408704);  // [8][256][1024] f32 split-K partials
  u16*   attnb = (u16*)(ws + 38797312);    // [256][1024] bf16

  k_pre<<<dim3(6144), dim3(256), 0, stream>>>(x, wq, wk, wv, wo, xn, wt);
  k_gemm_qkv<<<dim3(544), dim3(256), 0, stream>>>(xn, wt, kvb, qb);
  k_attn<<<dim3(256), dim3(256), 0, stream>>>(qb, kvb, attnb);
  k_gemm_o<<<dim3(128), dim3(256), 0, stream>>>(attnb, wt, part);
  k_finish<<<dim3(2048), dim3(256), 0, stream>>>(x, part, out);
}